// Round 1
// baseline (379.305 us; speedup 1.0000x reference)
//
#include <hip/hip_runtime.h>
#include <math.h>

typedef __bf16 bf16;
typedef __bf16 bf16x8 __attribute__((ext_vector_type(8)));
typedef __bf16 bf16x4 __attribute__((ext_vector_type(4)));
typedef float  f32x4  __attribute__((ext_vector_type(4)));

// Problem constants
#define NSAMP 64
#define DIMC 192
#define SAMP_ELEMS 196608   // 192*32*32
#define M_TOK 65536         // 64*1024 tokens

// ---- workspace layout (bytes) ----
constexpr size_t OFF_PART1  = 0;          // 64*16 float2 = 8 KB
constexpr size_t OFF_PART2  = 8192;
constexpr size_t OFF_BIASFV = 16384;      // 384 f32
constexpr size_t OFF_WFV    = 18432;      // 384*192 bf16 = 147456 B
constexpr size_t OFF_WPROJ  = OFF_WFV + 147456;     // 192*192 bf16
constexpr size_t OFF_WFC1   = OFF_WPROJ + 73728;    // 768*192 bf16
constexpr size_t OFF_WFC2   = OFF_WFC1 + 294912;    // 192*768 bf16
constexpr size_t OFF_XN     = 1048576;              // 65536*192 bf16 = 25165824 (GN1 out, reused for GN2 out)
constexpr size_t OFF_R      = OFF_XN + 25165824;    // big region, reused
constexpr size_t OFF_FV     = OFF_R;                // 65536*384 bf16 = 50331648
constexpr size_t OFF_Y      = OFF_R + 50331648;     // 65536*192 bf16 = 25165824
constexpr size_t OFF_HID    = OFF_R;                // 65536*768 bf16 = 100663296 (reuses FV+Y after they die)
constexpr size_t OFF_X1     = OFF_R + 100663296;    // 65536*192 f32 = 50331648
// total = 177,209,344 bytes

// ---------------- weight prep: fp32 -> bf16, transposed to [N][K] ----------------
__global__ __launch_bounds__(256) void prep_w(
    const float* __restrict__ f_w, const float* __restrict__ v_w,
    const float* __restrict__ proj_w, const float* __restrict__ fc1_w,
    const float* __restrict__ fc2_w, const float* __restrict__ f_b,
    const float* __restrict__ v_b,
    bf16* __restrict__ Wfv, bf16* __restrict__ Wproj,
    bf16* __restrict__ Wfc1, bf16* __restrict__ Wfc2,
    float* __restrict__ biasfv)
{
    const int i = blockIdx.x * 256 + threadIdx.x;
    if (i < 73728) {  // Wfv[384][192]: rows 0..191 = f_w ([O][C] already), 192..383 = v_w
        int o = i / 192, c = i % 192;
        Wfv[i] = (bf16)(o < 192 ? f_w[o * 192 + c] : v_w[(o - 192) * 192 + c]);
    }
    if (i < 36864) Wproj[i] = (bf16)proj_w[i];                    // [192][192], already [O][C]
    if (i < 147456) { int o = i / 192, k = i % 192; Wfc1[i] = (bf16)fc1_w[k * 768 + o]; } // fc1_w is [K][O]
    if (i < 147456) { int o = i / 768, k = i % 768; Wfc2[i] = (bf16)fc2_w[k * 192 + o]; } // fc2_w is [K][O]
    if (i < 384) biasfv[i] = i < 192 ? f_b[i] : v_b[i - 192];
}

// ---------------- GroupNorm stats (2-stage, deterministic) ----------------
__global__ __launch_bounds__(256) void gn_stats(const float* __restrict__ X, float2* __restrict__ part)
{
    const int b = blockIdx.y, seg = blockIdx.x;   // grid (16, 64)
    const float4* p = (const float4*)(X + (size_t)b * SAMP_ELEMS + (size_t)seg * 12288);
    float s = 0.f, q = 0.f;
    for (int i = threadIdx.x; i < 3072; i += 256) {
        float4 v = p[i];
        s += v.x + v.y + v.z + v.w;
        q += v.x * v.x + v.y * v.y + v.z * v.z + v.w * v.w;
    }
    __shared__ float bs[256], bq[256];
    const int t = threadIdx.x;
    bs[t] = s; bq[t] = q; __syncthreads();
    for (int off = 128; off > 0; off >>= 1) {
        if (t < off) { bs[t] += bs[t + off]; bq[t] += bq[t + off]; }
        __syncthreads();
    }
    if (t == 0) part[b * 16 + seg] = make_float2(bs[0], bq[0]);
}

__device__ inline float2 gn_mv(const float2* __restrict__ part, int b)
{
    float s = 0.f, q = 0.f;
#pragma unroll
    for (int i = 0; i < 16; ++i) { float2 v = part[b * 16 + i]; s += v.x; q += v.y; }
    const float mean = s * (1.f / (float)SAMP_ELEMS);
    const float var = q * (1.f / (float)SAMP_ELEMS) - mean * mean;
    float2 r; r.x = mean; r.y = rsqrtf(var + 1e-5f);
    return r;
}

// ---------------- GN1 normalize + NCHW->NHWC transpose -> bf16 ----------------
__global__ __launch_bounds__(256) void gn_norm_t(
    const float* __restrict__ X, const float2* __restrict__ part,
    const float* __restrict__ w, const float* __restrict__ bias, bf16* __restrict__ XN)
{
    // grid (16 psegs, 3 csegs, 64 b)
    const int b = blockIdx.z;
    const int p0 = blockIdx.x * 64, c0 = blockIdx.y * 64;
    const float2 mv = gn_mv(part, b);
    __shared__ float lds[64][65];
    const int tx = threadIdx.x & 63, ty = threadIdx.x >> 6;
    for (int cc = ty; cc < 64; cc += 4) {
        const int c = c0 + cc;
        const float v = X[((size_t)b * DIMC + c) * 1024 + p0 + tx];
        lds[cc][tx] = (v - mv.x) * mv.y * w[c] + bias[c];
    }
    __syncthreads();
    for (int pp = ty; pp < 64; pp += 4) {
        XN[((size_t)b * 1024 + p0 + pp) * DIMC + c0 + tx] = (bf16)lds[tx][pp];
    }
}

// ---------------- GN2 normalize (NHWC elementwise) -> bf16 ----------------
__global__ __launch_bounds__(256) void gn2_norm(
    const float* __restrict__ X1, const float2* __restrict__ part,
    const float* __restrict__ w, const float* __restrict__ bias, bf16* __restrict__ XN)
{
    const int b = blockIdx.y;                  // grid (48, 64)
    const float2 mv = gn_mv(part, b);
    const size_t base = (size_t)b * SAMP_ELEMS + (size_t)blockIdx.x * 4096;
#pragma unroll
    for (int i = 0; i < 4; ++i) {
        const size_t idx = base + (size_t)i * 1024 + threadIdx.x * 4;
        const float4 v = *(const float4*)(X1 + idx);
        const int c = (int)(idx % DIMC);       // groups of 4 never cross the 192 boundary
        bf16x4 o;
        o[0] = (bf16)((v.x - mv.x) * mv.y * w[c + 0] + bias[c + 0]);
        o[1] = (bf16)((v.y - mv.x) * mv.y * w[c + 1] + bias[c + 1]);
        o[2] = (bf16)((v.z - mv.x) * mv.y * w[c + 2] + bias[c + 2]);
        o[3] = (bf16)((v.w - mv.x) * mv.y * w[c + 3] + bias[c + 3]);
        *(bf16x4*)(XN + idx) = o;
    }
}

// ---------------- MFMA GEMM: C[M][N] = A[M][K] @ W[N][K]^T + bias, fused epilogues ----------------
// EPI 0: store bf16          (f/v conv)
// EPI 1: exact GELU -> bf16  (fc1)
// EPI 2: X1 = x_nchw + ls1*acc -> f32 NHWC (proj)
// EPI 3: d_out_nchw = X1 + ls2*acc        (fc2)
template<int EPI>
__global__ __launch_bounds__(256) void gemm_k(
    const bf16* __restrict__ A, const bf16* __restrict__ W,
    const float* __restrict__ bias, int N, int K,
    bf16* __restrict__ outb, float* __restrict__ outf,
    const float* __restrict__ resid, const float* __restrict__ ls)
{
    __shared__ uint4 sA[64 * 24];   // 64 rows x 192 bf16, XOR-swizzled 16B chunks
    __shared__ uint4 sW[64 * 24];
    const int t = threadIdx.x;
    const int m0 = blockIdx.y * 64;
    const int n0 = blockIdx.x * 64;
    const int lane = t & 63;
    const int wave = t >> 6;
    const int wm = wave >> 1, wn = wave & 1;   // 2x2 waves over the 64x64 tile
    const int lm = lane & 15, hi = lane >> 4;

    f32x4 acc00 = {0,0,0,0}, acc01 = {0,0,0,0}, acc10 = {0,0,0,0}, acc11 = {0,0,0,0};

    const int rA0 = wm * 32 + lm,      rA1 = wm * 32 + 16 + lm;
    const int rW0 = wn * 32 + lm,      rW1 = wn * 32 + 16 + lm;
    const bf16x8* fa = (const bf16x8*)sA;
    const bf16x8* fw = (const bf16x8*)sW;

    for (int kc = 0; kc < K; kc += 192) {
        for (int i = t; i < 64 * 24; i += 256) {
            const int r = i / 24, ci = i % 24;
            sA[r * 24 + (ci ^ (r & 7))] = *(const uint4*)(A + (size_t)(m0 + r) * K + kc + ci * 8);
            sW[r * 24 + (ci ^ (r & 7))] = *(const uint4*)(W + (size_t)(n0 + r) * K + kc + ci * 8);
        }
        __syncthreads();
#pragma unroll
        for (int ks = 0; ks < 6; ++ks) {
            const int cb = ks * 4 + hi;
            bf16x8 a0 = fa[rA0 * 24 + (cb ^ (rA0 & 7))];
            bf16x8 a1 = fa[rA1 * 24 + (cb ^ (rA1 & 7))];
            bf16x8 w0 = fw[rW0 * 24 + (cb ^ (rW0 & 7))];
            bf16x8 w1 = fw[rW1 * 24 + (cb ^ (rW1 & 7))];
            acc00 = __builtin_amdgcn_mfma_f32_16x16x32_bf16(a0, w0, acc00, 0, 0, 0);
            acc01 = __builtin_amdgcn_mfma_f32_16x16x32_bf16(a0, w1, acc01, 0, 0, 0);
            acc10 = __builtin_amdgcn_mfma_f32_16x16x32_bf16(a1, w0, acc10, 0, 0, 0);
            acc11 = __builtin_amdgcn_mfma_f32_16x16x32_bf16(a1, w1, acc11, 0, 0, 0);
        }
        __syncthreads();
    }

    // epilogue: D row = (lane>>4)*4 + j, col = lane&15 (verified gfx950 layout)
#pragma unroll
    for (int mt = 0; mt < 2; ++mt) {
#pragma unroll
        for (int nt = 0; nt < 2; ++nt) {
            f32x4 av = mt == 0 ? (nt == 0 ? acc00 : acc01) : (nt == 0 ? acc10 : acc11);
            const int nc = n0 + wn * 32 + nt * 16 + lm;
            const int mr = m0 + wm * 32 + mt * 16 + hi * 4;
            const float bv = bias[nc];
#pragma unroll
            for (int j = 0; j < 4; ++j) {
                const int m = mr + j;
                const float v = av[j] + bv;
                if constexpr (EPI == 0) {
                    outb[(size_t)m * N + nc] = (bf16)v;
                } else if constexpr (EPI == 1) {
                    const float g = 0.5f * v * (1.f + erff(v * 0.70710678118654752f));
                    outb[(size_t)m * N + nc] = (bf16)g;
                } else if constexpr (EPI == 2) {
                    const int bb = m >> 10, p = m & 1023;
                    const float xv = resid[((size_t)bb * DIMC + nc) * 1024 + p];  // x NCHW
                    outf[(size_t)m * DIMC + nc] = xv + ls[nc] * v;                // X1 NHWC f32
                } else {
                    const float x1v = resid[(size_t)m * DIMC + nc];               // X1 NHWC
                    const int bb = m >> 10, p = m & 1023;
                    outf[((size_t)bb * DIMC + nc) * 1024 + p] = x1v + ls[nc] * v; // d_out NCHW
                }
            }
        }
    }
}

// ---------------- cluster: one block per (b, head, fold1, fold2) group ----------------
__global__ __launch_bounds__(256) void cluster_k(
    const bf16* __restrict__ FV, bf16* __restrict__ Y,
    const float* __restrict__ alpha_p, const float* __restrict__ beta_p)
{
    __shared__ float lf[256][25];   // +1 pad: stride 25 is coprime with 32 banks
    __shared__ float lv[256][25];
    __shared__ float cf[4][24], cv[4][24], cinv[4];
    __shared__ float lsim[256];
    __shared__ int   lbest[256];
    __shared__ float agg[4][24];

    const int g = blockIdx.x;                        // 2048 groups
    const int bb = g >> 5, e = (g >> 2) & 7, f1 = (g >> 1) & 1, f2 = g & 1;
    const int t = threadIdx.x;                       // token n = wi*16 + hi
    const int wi = t >> 4, hj = t & 15;
    const int p = (f1 * 16 + wi) * 32 + (f2 * 16 + hj);
    const size_t tok = (size_t)bb * 1024 + p;

    // load 24 f + 24 v channels of this head (bf16x8 x3 each)
    const bf16x8* src = (const bf16x8*)(FV + tok * 384);
    bf16x8 hf0 = src[e * 3 + 0], hf1 = src[e * 3 + 1], hf2 = src[e * 3 + 2];
    bf16x8 hv0 = src[24 + e * 3 + 0], hv1 = src[24 + e * 3 + 1], hv2 = src[24 + e * 3 + 2];
    float freg[24];
#pragma unroll
    for (int j = 0; j < 8; ++j) {
        const float a0 = (float)hf0[j], a1 = (float)hf1[j], a2 = (float)hf2[j];
        freg[j] = a0; freg[8 + j] = a1; freg[16 + j] = a2;
        lf[t][j] = a0; lf[t][8 + j] = a1; lf[t][16 + j] = a2;
        lv[t][j] = (float)hv0[j]; lv[t][8 + j] = (float)hv1[j]; lv[t][16 + j] = (float)hv2[j];
    }
    __syncthreads();

    // centers: AdaptiveAvgPool2d(2,2) over 8x8 token blocks (f and v)
    if (t < 192) {
        const int team = t / 96;        // 0: f, 1: v
        const int idx = t % 96;
        const int m = idx / 24, c = idx % 24;
        const int pw = m >> 1, ph = m & 1;
        float s = 0.f;
        for (int a = 0; a < 8; ++a) {
            const int nb = (pw * 8 + a) * 16 + ph * 8;
#pragma unroll
            for (int bj = 0; bj < 8; ++bj)
                s += team ? lv[nb + bj][c] : lf[nb + bj][c];
        }
        if (team) cv[m][c] = s * (1.f / 64.f);
        else      cf[m][c] = s * (1.f / 64.f);
    }
    __syncthreads();
    if (t < 4) {
        float s = 0.f;
#pragma unroll
        for (int c = 0; c < 24; ++c) s += cf[t][c] * cf[t][c];
        cinv[t] = 1.f / fmaxf(sqrtf(s), 1e-12f);
    }
    __syncthreads();

    // per-token: cosine sim to 4 centers, sigmoid, hard argmax (first-max ties)
    float nrm = 0.f;
#pragma unroll
    for (int c = 0; c < 24; ++c) nrm += freg[c] * freg[c];
    const float invf = 1.f / fmaxf(sqrtf(nrm), 1e-12f);
    const float alpha = alpha_p[0], beta = beta_p[0];
    float bestv = -1.f; int best = 0;
    for (int m = 0; m < 4; ++m) {
        float d = 0.f;
#pragma unroll
        for (int c = 0; c < 24; ++c) d += cf[m][c] * freg[c];
        const float z = beta + alpha * d * cinv[m] * invf;
        const float sim = 1.f / (1.f + expf(-z));
        if (sim > bestv) { bestv = sim; best = m; }
    }
    lsim[t] = bestv; lbest[t] = best;
    __syncthreads();

    // agg[m][c] = (sum_{n: best==m} sim_n * v[n][c] + value_center) / (count+1) — deterministic loop
    if (t < 96) {
        const int m = t / 24, c = t % 24;
        float s = 0.f; int cnt = 0;
        for (int n = 0; n < 256; ++n) {
            if (lbest[n] == m) { s += lsim[n] * lv[n][c]; ++cnt; }
        }
        agg[m][c] = (s + cv[m][c]) / ((float)cnt + 1.f);
    }
    __syncthreads();

    // dispatch back: out[n][c] = agg[best_n][c] * sim_n
    const float sv = lsim[t]; const int bm = lbest[t];
    bf16x8 o0, o1, o2;
#pragma unroll
    for (int j = 0; j < 8; ++j) {
        o0[j] = (bf16)(agg[bm][j] * sv);
        o1[j] = (bf16)(agg[bm][8 + j] * sv);
        o2[j] = (bf16)(agg[bm][16 + j] * sv);
    }
    bf16x8* dst = (bf16x8*)(Y + tok * DIMC + e * 24);
    dst[0] = o0; dst[1] = o1; dst[2] = o2;
}

// ---------------- launch ----------------
extern "C" void kernel_launch(void* const* d_in, const int* in_sizes, int n_in,
                              void* d_out, int out_size, void* d_ws, size_t ws_size,
                              hipStream_t stream)
{
    (void)in_sizes; (void)n_in; (void)out_size; (void)ws_size;
    const float* x      = (const float*)d_in[0];
    const float* gn1_w  = (const float*)d_in[1];
    const float* gn1_b  = (const float*)d_in[2];
    const float* f_w    = (const float*)d_in[3];
    const float* f_b    = (const float*)d_in[4];
    const float* v_w    = (const float*)d_in[5];
    const float* v_b    = (const float*)d_in[6];
    const float* proj_w = (const float*)d_in[7];
    const float* proj_b = (const float*)d_in[8];
    const float* alpha  = (const float*)d_in[9];
    const float* beta   = (const float*)d_in[10];
    const float* ls1    = (const float*)d_in[11];
    const float* gn2_w  = (const float*)d_in[12];
    const float* gn2_b  = (const float*)d_in[13];
    const float* fc1_w  = (const float*)d_in[14];
    const float* fc1_b  = (const float*)d_in[15];
    const float* fc2_w  = (const float*)d_in[16];
    const float* fc2_b  = (const float*)d_in[17];
    const float* ls2    = (const float*)d_in[18];

    char* ws = (char*)d_ws;
    float2* part1 = (float2*)(ws + OFF_PART1);
    float2* part2 = (float2*)(ws + OFF_PART2);
    float* biasfv = (float*)(ws + OFF_BIASFV);
    bf16* Wfv   = (bf16*)(ws + OFF_WFV);
    bf16* Wproj = (bf16*)(ws + OFF_WPROJ);
    bf16* Wfc1  = (bf16*)(ws + OFF_WFC1);
    bf16* Wfc2  = (bf16*)(ws + OFF_WFC2);
    bf16* XN    = (bf16*)(ws + OFF_XN);
    bf16* FVb   = (bf16*)(ws + OFF_FV);
    bf16* Yb    = (bf16*)(ws + OFF_Y);
    bf16* HID   = (bf16*)(ws + OFF_HID);
    float* X1   = (float*)(ws + OFF_X1);
    float* out  = (float*)d_out;

    prep_w<<<576, 256, 0, stream>>>(f_w, v_w, proj_w, fc1_w, fc2_w, f_b, v_b,
                                    Wfv, Wproj, Wfc1, Wfc2, biasfv);
    gn_stats<<<dim3(16, 64), 256, 0, stream>>>(x, part1);
    gn_norm_t<<<dim3(16, 3, 64), 256, 0, stream>>>(x, part1, gn1_w, gn1_b, XN);
    gemm_k<0><<<dim3(6, 1024), 256, 0, stream>>>(XN, Wfv, biasfv, 384, 192,
                                                 FVb, nullptr, nullptr, nullptr);
    cluster_k<<<2048, 256, 0, stream>>>(FVb, Yb, alpha, beta);
    gemm_k<2><<<dim3(3, 1024), 256, 0, stream>>>(Yb, Wproj, proj_b, 192, 192,
                                                 nullptr, X1, x, ls1);
    gn_stats<<<dim3(16, 64), 256, 0, stream>>>(X1, part2);
    gn2_norm<<<dim3(48, 64), 256, 0, stream>>>(X1, part2, gn2_w, gn2_b, XN);
    gemm_k<1><<<dim3(12, 1024), 256, 0, stream>>>(XN, Wfc1, fc1_b, 768, 192,
                                                  HID, nullptr, nullptr, nullptr);
    gemm_k<3><<<dim3(3, 1024), 256, 0, stream>>>(HID, Wfc2, fc2_b, 192, 768,
                                                 nullptr, out, X1, ls2);
}

// Round 2
// 313.429 us; speedup vs baseline: 1.2102x; 1.2102x over previous
//
#include <hip/hip_runtime.h>
#include <math.h>

typedef __bf16 bf16;
typedef __bf16 bf16x8 __attribute__((ext_vector_type(8)));
typedef __bf16 bf16x4 __attribute__((ext_vector_type(4)));
typedef float  f32x4  __attribute__((ext_vector_type(4)));

// Problem constants
#define NSAMP 64
#define DIMC 192
#define SAMP_ELEMS 196608   // 192*32*32
#define M_TOK 65536         // 64*1024 tokens

// ---- workspace layout (bytes) ----
constexpr size_t OFF_PART1  = 0;          // 64*16 float2 = 8 KB
constexpr size_t OFF_PART2  = 8192;
constexpr size_t OFF_BIASFV = 16384;      // 384 f32
constexpr size_t OFF_WFV    = 18432;      // 384*192 bf16 = 147456 B
constexpr size_t OFF_WPROJ  = OFF_WFV + 147456;     // 192*192 bf16
constexpr size_t OFF_WFC1   = OFF_WPROJ + 73728;    // 768*192 bf16
constexpr size_t OFF_WFC2   = OFF_WFC1 + 294912;    // 192*768 bf16
constexpr size_t OFF_XN     = 1048576;              // 65536*192 bf16 = 25165824 (GN1 out, reused for GN2 out)
constexpr size_t OFF_R      = OFF_XN + 25165824;    // big region, reused
constexpr size_t OFF_FV     = OFF_R;                // 65536*384 bf16 = 50331648
constexpr size_t OFF_Y      = OFF_R + 50331648;     // 65536*192 bf16 = 25165824
constexpr size_t OFF_HID    = OFF_R;                // 65536*768 bf16 = 100663296 (reuses FV+Y after they die)
constexpr size_t OFF_X1     = OFF_R + 100663296;    // 65536*192 f32 = 50331648
// total = 177,209,344 bytes

// ---------------- weight prep: fp32 -> bf16, transposed to [N][K] ----------------
__global__ __launch_bounds__(256) void prep_w(
    const float* __restrict__ f_w, const float* __restrict__ v_w,
    const float* __restrict__ proj_w, const float* __restrict__ fc1_w,
    const float* __restrict__ fc2_w, const float* __restrict__ f_b,
    const float* __restrict__ v_b,
    bf16* __restrict__ Wfv, bf16* __restrict__ Wproj,
    bf16* __restrict__ Wfc1, bf16* __restrict__ Wfc2,
    float* __restrict__ biasfv)
{
    const int i = blockIdx.x * 256 + threadIdx.x;
    if (i < 73728) {  // Wfv[384][192]: rows 0..191 = f_w ([O][C] already), 192..383 = v_w
        int o = i / 192, c = i % 192;
        Wfv[i] = (bf16)(o < 192 ? f_w[o * 192 + c] : v_w[(o - 192) * 192 + c]);
    }
    if (i < 36864) Wproj[i] = (bf16)proj_w[i];                    // [192][192], already [O][C]
    if (i < 147456) { int o = i / 192, k = i % 192; Wfc1[i] = (bf16)fc1_w[k * 768 + o]; } // fc1_w is [K][O]
    if (i < 147456) { int o = i / 768, k = i % 768; Wfc2[i] = (bf16)fc2_w[k * 192 + o]; } // fc2_w is [K][O]
    if (i < 384) biasfv[i] = i < 192 ? f_b[i] : v_b[i - 192];
}

// ---------------- GroupNorm stats (2-stage, deterministic) ----------------
__global__ __launch_bounds__(256) void gn_stats(const float* __restrict__ X, float2* __restrict__ part)
{
    const int b = blockIdx.y, seg = blockIdx.x;   // grid (16, 64)
    const float4* p = (const float4*)(X + (size_t)b * SAMP_ELEMS + (size_t)seg * 12288);
    float s = 0.f, q = 0.f;
    for (int i = threadIdx.x; i < 3072; i += 256) {
        float4 v = p[i];
        s += v.x + v.y + v.z + v.w;
        q += v.x * v.x + v.y * v.y + v.z * v.z + v.w * v.w;
    }
    __shared__ float bs[256], bq[256];
    const int t = threadIdx.x;
    bs[t] = s; bq[t] = q; __syncthreads();
    for (int off = 128; off > 0; off >>= 1) {
        if (t < off) { bs[t] += bs[t + off]; bq[t] += bq[t + off]; }
        __syncthreads();
    }
    if (t == 0) part[b * 16 + seg] = make_float2(bs[0], bq[0]);
}

__device__ inline float2 gn_mv(const float2* __restrict__ part, int b)
{
    float s = 0.f, q = 0.f;
#pragma unroll
    for (int i = 0; i < 16; ++i) { float2 v = part[b * 16 + i]; s += v.x; q += v.y; }
    const float mean = s * (1.f / (float)SAMP_ELEMS);
    const float var = q * (1.f / (float)SAMP_ELEMS) - mean * mean;
    float2 r; r.x = mean; r.y = rsqrtf(var + 1e-5f);
    return r;
}

// ---------------- GN1 normalize + NCHW->NHWC transpose -> bf16 ----------------
__global__ __launch_bounds__(256) void gn_norm_t(
    const float* __restrict__ X, const float2* __restrict__ part,
    const float* __restrict__ w, const float* __restrict__ bias, bf16* __restrict__ XN)
{
    // grid (16 psegs, 3 csegs, 64 b)
    const int b = blockIdx.z;
    const int p0 = blockIdx.x * 64, c0 = blockIdx.y * 64;
    const float2 mv = gn_mv(part, b);
    __shared__ float lds[64][65];
    const int tx = threadIdx.x & 63, ty = threadIdx.x >> 6;
    for (int cc = ty; cc < 64; cc += 4) {
        const int c = c0 + cc;
        const float v = X[((size_t)b * DIMC + c) * 1024 + p0 + tx];
        lds[cc][tx] = (v - mv.x) * mv.y * w[c] + bias[c];
    }
    __syncthreads();
    for (int pp = ty; pp < 64; pp += 4) {
        XN[((size_t)b * 1024 + p0 + pp) * DIMC + c0 + tx] = (bf16)lds[tx][pp];
    }
}

// ---------------- GN2 normalize (NHWC elementwise) -> bf16 ----------------
__global__ __launch_bounds__(256) void gn2_norm(
    const float* __restrict__ X1, const float2* __restrict__ part,
    const float* __restrict__ w, const float* __restrict__ bias, bf16* __restrict__ XN)
{
    const int b = blockIdx.y;                  // grid (48, 64)
    const float2 mv = gn_mv(part, b);
    const size_t base = (size_t)b * SAMP_ELEMS + (size_t)blockIdx.x * 4096;
#pragma unroll
    for (int i = 0; i < 4; ++i) {
        const size_t idx = base + (size_t)i * 1024 + threadIdx.x * 4;
        const float4 v = *(const float4*)(X1 + idx);
        const int c = (int)(idx % DIMC);       // groups of 4 never cross the 192 boundary
        bf16x4 o;
        o[0] = (bf16)((v.x - mv.x) * mv.y * w[c + 0] + bias[c + 0]);
        o[1] = (bf16)((v.y - mv.x) * mv.y * w[c + 1] + bias[c + 1]);
        o[2] = (bf16)((v.z - mv.x) * mv.y * w[c + 2] + bias[c + 2]);
        o[3] = (bf16)((v.w - mv.x) * mv.y * w[c + 3] + bias[c + 3]);
        *(bf16x4*)(XN + idx) = o;
    }
}

// ---------------- MFMA GEMM: C[M][N] = A[M][K] @ W[N][K]^T + bias, fused epilogues ----------------
// EPI 0: store bf16          (f/v conv)
// EPI 1: exact GELU -> bf16  (fc1)
// EPI 2: X1 = x_nchw + ls1*acc -> f32 NHWC (proj)
// EPI 3: d_out_nchw = X1 + ls2*acc        (fc2)
template<int EPI>
__global__ __launch_bounds__(256) void gemm_k(
    const bf16* __restrict__ A, const bf16* __restrict__ W,
    const float* __restrict__ bias, int N, int K,
    bf16* __restrict__ outb, float* __restrict__ outf,
    const float* __restrict__ resid, const float* __restrict__ ls)
{
    __shared__ uint4 sA[64 * 24];   // 64 rows x 192 bf16, XOR-swizzled 16B chunks
    __shared__ uint4 sW[64 * 24];
    const int t = threadIdx.x;
    const int m0 = blockIdx.y * 64;
    const int n0 = blockIdx.x * 64;
    const int lane = t & 63;
    const int wave = t >> 6;
    const int wm = wave >> 1, wn = wave & 1;   // 2x2 waves over the 64x64 tile
    const int lm = lane & 15, hi = lane >> 4;

    f32x4 acc00 = {0,0,0,0}, acc01 = {0,0,0,0}, acc10 = {0,0,0,0}, acc11 = {0,0,0,0};

    const int rA0 = wm * 32 + lm,      rA1 = wm * 32 + 16 + lm;
    const int rW0 = wn * 32 + lm,      rW1 = wn * 32 + 16 + lm;
    const bf16x8* fa = (const bf16x8*)sA;
    const bf16x8* fw = (const bf16x8*)sW;

    for (int kc = 0; kc < K; kc += 192) {
        for (int i = t; i < 64 * 24; i += 256) {
            const int r = i / 24, ci = i % 24;
            sA[r * 24 + (ci ^ (r & 7))] = *(const uint4*)(A + (size_t)(m0 + r) * K + kc + ci * 8);
            sW[r * 24 + (ci ^ (r & 7))] = *(const uint4*)(W + (size_t)(n0 + r) * K + kc + ci * 8);
        }
        __syncthreads();
#pragma unroll
        for (int ks = 0; ks < 6; ++ks) {
            const int cb = ks * 4 + hi;
            bf16x8 a0 = fa[rA0 * 24 + (cb ^ (rA0 & 7))];
            bf16x8 a1 = fa[rA1 * 24 + (cb ^ (rA1 & 7))];
            bf16x8 w0 = fw[rW0 * 24 + (cb ^ (rW0 & 7))];
            bf16x8 w1 = fw[rW1 * 24 + (cb ^ (rW1 & 7))];
            acc00 = __builtin_amdgcn_mfma_f32_16x16x32_bf16(a0, w0, acc00, 0, 0, 0);
            acc01 = __builtin_amdgcn_mfma_f32_16x16x32_bf16(a0, w1, acc01, 0, 0, 0);
            acc10 = __builtin_amdgcn_mfma_f32_16x16x32_bf16(a1, w0, acc10, 0, 0, 0);
            acc11 = __builtin_amdgcn_mfma_f32_16x16x32_bf16(a1, w1, acc11, 0, 0, 0);
        }
        __syncthreads();
    }

    // epilogue: D row = (lane>>4)*4 + j, col = lane&15 (verified gfx950 layout)
#pragma unroll
    for (int mt = 0; mt < 2; ++mt) {
#pragma unroll
        for (int nt = 0; nt < 2; ++nt) {
            f32x4 av = mt == 0 ? (nt == 0 ? acc00 : acc01) : (nt == 0 ? acc10 : acc11);
            const int nc = n0 + wn * 32 + nt * 16 + lm;
            const int mr = m0 + wm * 32 + mt * 16 + hi * 4;
            const float bv = bias[nc];
#pragma unroll
            for (int j = 0; j < 4; ++j) {
                const int m = mr + j;
                const float v = av[j] + bv;
                if constexpr (EPI == 0) {
                    outb[(size_t)m * N + nc] = (bf16)v;
                } else if constexpr (EPI == 1) {
                    const float g = 0.5f * v * (1.f + erff(v * 0.70710678118654752f));
                    outb[(size_t)m * N + nc] = (bf16)g;
                } else if constexpr (EPI == 2) {
                    const int bb = m >> 10, p = m & 1023;
                    const float xv = resid[((size_t)bb * DIMC + nc) * 1024 + p];  // x NCHW
                    outf[(size_t)m * DIMC + nc] = xv + ls[nc] * v;                // X1 NHWC f32
                } else {
                    const float x1v = resid[(size_t)m * DIMC + nc];               // X1 NHWC
                    const int bb = m >> 10, p = m & 1023;
                    outf[((size_t)bb * DIMC + nc) * 1024 + p] = x1v + ls[nc] * v; // d_out NCHW
                }
            }
        }
    }
}

// ---------------- cluster: one block per (b, head, fold1, fold2) group ----------------
// Rewritten: 30 KB LDS (union of bf16 stage / f32 sim*v table), segmented parallel
// aggregation (serial length 32+8 instead of 256), ballot-based counts, no idle-phase
// barriers for center norms (folded into per-thread sim loop).
__global__ __launch_bounds__(256) void cluster_k(
    const bf16* __restrict__ FV, bf16* __restrict__ Y,
    const float* __restrict__ alpha_p, const float* __restrict__ beta_p)
{
    __shared__ __align__(16) char u_raw[25600];  // phase A: bf16 lfv[256][48]; phase B: f32 pv[256][25]
    __shared__ float cf[4][24], cv[4][24];
    __shared__ float partial[8][4][24];
    __shared__ int   cntp[4][4];                 // [wave][m]
    __shared__ float aggL[4][24];
    __shared__ int   bestL[256];

    const int g = blockIdx.x;                    // 2048 groups
    const int bb = g >> 5, e = (g >> 2) & 7, f1 = (g >> 1) & 1, f2 = g & 1;
    const int t = threadIdx.x;                   // token n = wi*16 + hj
    const int wi = t >> 4, hj = t & 15;
    const int p = (f1 * 16 + wi) * 32 + (f2 * 16 + hj);
    const size_t tok = (size_t)bb * 1024 + p;

    // load 24 f + 24 v channels of this head
    const bf16x8* src = (const bf16x8*)(FV + tok * 384);
    bf16x8 hf0 = src[e * 3 + 0], hf1 = src[e * 3 + 1], hf2 = src[e * 3 + 2];
    bf16x8 hv0 = src[24 + e * 3 + 0], hv1 = src[24 + e * 3 + 1], hv2 = src[24 + e * 3 + 2];

    // stage raw bf16 into LDS for pooling (lossless)
    bf16* lfv = (bf16*)u_raw;                    // [256][48]
    {
        bf16x8* row = (bf16x8*)(lfv + t * 48);
        row[0] = hf0; row[1] = hf1; row[2] = hf2;
        row[3] = hv0; row[4] = hv1; row[5] = hv2;
    }
    float freg[24];
#pragma unroll
    for (int j = 0; j < 8; ++j) {
        freg[j] = (float)hf0[j]; freg[8 + j] = (float)hf1[j]; freg[16 + j] = (float)hf2[j];
    }
    __syncthreads();

    // centers: AdaptiveAvgPool2d(2,2) over 8x8 token blocks (f and v), 192 threads
    if (t < 192) {
        const int team = t / 96;                 // 0: f, 1: v
        const int idx = t % 96;
        const int m = idx / 24, c = idx % 24;
        const int pw = m >> 1, ph = m & 1;
        float s = 0.f;
        for (int a = 0; a < 8; ++a) {
            const int nb = (pw * 8 + a) * 16 + ph * 8;
#pragma unroll
            for (int bj = 0; bj < 8; ++bj)
                s += (float)lfv[(nb + bj) * 48 + team * 24 + c];
        }
        if (team) cv[m][c] = s * (1.f / 64.f);
        else      cf[m][c] = s * (1.f / 64.f);
    }
    __syncthreads();   // lfv reads complete; cf/cv visible

    // per-token: cosine sim to 4 centers (center norm folded in), sigmoid, argmax (first-max ties)
    float nrm = 0.f;
#pragma unroll
    for (int c = 0; c < 24; ++c) nrm += freg[c] * freg[c];
    const float invf = 1.f / fmaxf(sqrtf(nrm), 1e-12f);
    const float alpha = alpha_p[0], beta = beta_p[0];
    float bestv = -1.f; int best = 0;
#pragma unroll
    for (int m = 0; m < 4; ++m) {
        float d = 0.f, cs = 0.f;
#pragma unroll
        for (int c = 0; c < 24; ++c) {
            const float cfv = cf[m][c];
            d += cfv * freg[c];
            cs += cfv * cfv;
        }
        const float z = beta + alpha * d * (1.f / fmaxf(sqrtf(cs), 1e-12f)) * invf;
        const float sim = 1.f / (1.f + expf(-z));
        if (sim > bestv) { bestv = sim; best = m; }
    }

    // per-wave counts via ballot (deterministic)
    {
        const unsigned long long m0 = __ballot(best == 0);
        const unsigned long long m1 = __ballot(best == 1);
        const unsigned long long m2 = __ballot(best == 2);
        const unsigned long long m3 = __ballot(best == 3);
        if ((t & 63) == 0) {
            const int w = t >> 6;
            cntp[w][0] = __popcll(m0); cntp[w][1] = __popcll(m1);
            cntp[w][2] = __popcll(m2); cntp[w][3] = __popcll(m3);
        }
    }

    // pre-multiplied sim*v table (overwrites lfv region — reads done at last barrier)
    float (*pvL)[25] = (float (*)[25])u_raw;
#pragma unroll
    for (int j = 0; j < 8; ++j) {
        pvL[t][j]      = bestv * (float)hv0[j];
        pvL[t][8 + j]  = bestv * (float)hv1[j];
        pvL[t][16 + j] = bestv * (float)hv2[j];
    }
    bestL[t] = best;
    __syncthreads();

    // segmented aggregation: 192 threads = (seg 0..7) x (c 0..23), branch-free selects
    if (t < 192) {
        const int seg = t / 24, c = t % 24;
        float a0 = 0.f, a1 = 0.f, a2 = 0.f, a3 = 0.f;
        const int nb = seg * 32;
        for (int i = 0; i < 32; ++i) {
            const int n = nb + i;
            const int bm = bestL[n];
            const float x = pvL[n][c];
            a0 += (bm == 0) ? x : 0.f;
            a1 += (bm == 1) ? x : 0.f;
            a2 += (bm == 2) ? x : 0.f;
            a3 += (bm == 3) ? x : 0.f;
        }
        partial[seg][0][c] = a0; partial[seg][1][c] = a1;
        partial[seg][2][c] = a2; partial[seg][3][c] = a3;
    }
    __syncthreads();

    // combine partials + value centers, divide by (count+1)
    if (t < 96) {
        const int m = t / 24, c = t % 24;
        float s = 0.f;
#pragma unroll
        for (int seg = 0; seg < 8; ++seg) s += partial[seg][m][c];
        const int cnt = cntp[0][m] + cntp[1][m] + cntp[2][m] + cntp[3][m];
        aggL[m][c] = (s + cv[m][c]) / ((float)cnt + 1.f);
    }
    __syncthreads();

    // dispatch back: out[n][c] = agg[best_n][c] * sim_n
    const float sv = bestv; const int bm = best;
    bf16x8 o0, o1, o2;
#pragma unroll
    for (int j = 0; j < 8; ++j) {
        o0[j] = (bf16)(aggL[bm][j] * sv);
        o1[j] = (bf16)(aggL[bm][8 + j] * sv);
        o2[j] = (bf16)(aggL[bm][16 + j] * sv);
    }
    bf16x8* dst = (bf16x8*)(Y + tok * DIMC + e * 24);
    dst[0] = o0; dst[1] = o1; dst[2] = o2;
}

// ---------------- launch ----------------
extern "C" void kernel_launch(void* const* d_in, const int* in_sizes, int n_in,
                              void* d_out, int out_size, void* d_ws, size_t ws_size,
                              hipStream_t stream)
{
    (void)in_sizes; (void)n_in; (void)out_size; (void)ws_size;
    const float* x      = (const float*)d_in[0];
    const float* gn1_w  = (const float*)d_in[1];
    const float* gn1_b  = (const float*)d_in[2];
    const float* f_w    = (const float*)d_in[3];
    const float* f_b    = (const float*)d_in[4];
    const float* v_w    = (const float*)d_in[5];
    const float* v_b    = (const float*)d_in[6];
    const float* proj_w = (const float*)d_in[7];
    const float* proj_b = (const float*)d_in[8];
    const float* alpha  = (const float*)d_in[9];
    const float* beta   = (const float*)d_in[10];
    const float* ls1    = (const float*)d_in[11];
    const float* gn2_w  = (const float*)d_in[12];
    const float* gn2_b  = (const float*)d_in[13];
    const float* fc1_w  = (const float*)d_in[14];
    const float* fc1_b  = (const float*)d_in[15];
    const float* fc2_w  = (const float*)d_in[16];
    const float* fc2_b  = (const float*)d_in[17];
    const float* ls2    = (const float*)d_in[18];

    char* ws = (char*)d_ws;
    float2* part1 = (float2*)(ws + OFF_PART1);
    float2* part2 = (float2*)(ws + OFF_PART2);
    float* biasfv = (float*)(ws + OFF_BIASFV);
    bf16* Wfv   = (bf16*)(ws + OFF_WFV);
    bf16* Wproj = (bf16*)(ws + OFF_WPROJ);
    bf16* Wfc1  = (bf16*)(ws + OFF_WFC1);
    bf16* Wfc2  = (bf16*)(ws + OFF_WFC2);
    bf16* XN    = (bf16*)(ws + OFF_XN);
    bf16* FVb   = (bf16*)(ws + OFF_FV);
    bf16* Yb    = (bf16*)(ws + OFF_Y);
    bf16* HID   = (bf16*)(ws + OFF_HID);
    float* X1   = (float*)(ws + OFF_X1);
    float* out  = (float*)d_out;

    prep_w<<<576, 256, 0, stream>>>(f_w, v_w, proj_w, fc1_w, fc2_w, f_b, v_b,
                                    Wfv, Wproj, Wfc1, Wfc2, biasfv);
    gn_stats<<<dim3(16, 64), 256, 0, stream>>>(x, part1);
    gn_norm_t<<<dim3(16, 3, 64), 256, 0, stream>>>(x, part1, gn1_w, gn1_b, XN);
    gemm_k<0><<<dim3(6, 1024), 256, 0, stream>>>(XN, Wfv, biasfv, 384, 192,
                                                 FVb, nullptr, nullptr, nullptr);
    cluster_k<<<2048, 256, 0, stream>>>(FVb, Yb, alpha, beta);
    gemm_k<2><<<dim3(3, 1024), 256, 0, stream>>>(Yb, Wproj, proj_b, 192, 192,
                                                 nullptr, X1, x, ls1);
    gn_stats<<<dim3(16, 64), 256, 0, stream>>>(X1, part2);
    gn2_norm<<<dim3(48, 64), 256, 0, stream>>>(X1, part2, gn2_w, gn2_b, XN);
    gemm_k<1><<<dim3(12, 1024), 256, 0, stream>>>(XN, Wfc1, fc1_b, 768, 192,
                                                  HID, nullptr, nullptr, nullptr);
    gemm_k<3><<<dim3(3, 1024), 256, 0, stream>>>(HID, Wfc2, fc2_b, 192, 768,
                                                 nullptr, out, X1, ls2);
}

// Round 3
// 293.942 us; speedup vs baseline: 1.2904x; 1.0663x over previous
//
#include <hip/hip_runtime.h>
#include <math.h>

typedef __bf16 bf16;
typedef __bf16 bf16x8 __attribute__((ext_vector_type(8)));
typedef __bf16 bf16x4 __attribute__((ext_vector_type(4)));
typedef float  f32x4  __attribute__((ext_vector_type(4)));

union bfu { bf16x8 h; uint4 u; };

// Problem constants
#define NSAMP 64
#define DIMC 192
#define SAMP_ELEMS 196608   // 192*32*32
#define M_TOK 65536         // 64*1024 tokens

// ---- workspace layout (bytes) ----
constexpr size_t OFF_PART1  = 0;          // 64*16 float2
constexpr size_t OFF_PART2  = 8192;       // 64*48 float2 = 24576
constexpr size_t OFF_BIASFV = 40960;      // 384 f32
constexpr size_t OFF_WFV    = 43008;      // 384*192 bf16 = 147456 B
constexpr size_t OFF_WPROJ  = OFF_WFV + 147456;     // 192*192 bf16
constexpr size_t OFF_WFC1   = OFF_WPROJ + 73728;    // 768*192 bf16
constexpr size_t OFF_WFC2   = OFF_WFC1 + 294912;    // 192*768 bf16
constexpr size_t OFF_XN     = 1048576;              // 65536*192 bf16 (GN1 out)
constexpr size_t OFF_R      = OFF_XN + 25165824;
constexpr size_t OFF_FV     = OFF_R;                // 65536*384 bf16 = 50331648
constexpr size_t OFF_Y      = OFF_R + 50331648;     // 65536*192 bf16
constexpr size_t OFF_X1     = OFF_R + 100663296;    // 65536*192 f32 = 50331648

// ---------------- weight prep: fp32 -> bf16, transposed to [N][K] ----------------
__global__ __launch_bounds__(256) void prep_w(
    const float* __restrict__ f_w, const float* __restrict__ v_w,
    const float* __restrict__ proj_w, const float* __restrict__ fc1_w,
    const float* __restrict__ fc2_w, const float* __restrict__ f_b,
    const float* __restrict__ v_b,
    bf16* __restrict__ Wfv, bf16* __restrict__ Wproj,
    bf16* __restrict__ Wfc1, bf16* __restrict__ Wfc2,
    float* __restrict__ biasfv)
{
    const int i = blockIdx.x * 256 + threadIdx.x;
    if (i < 73728) {  // Wfv[384][192]
        int o = i / 192, c = i % 192;
        Wfv[i] = (bf16)(o < 192 ? f_w[o * 192 + c] : v_w[(o - 192) * 192 + c]);
    }
    if (i < 36864) Wproj[i] = (bf16)proj_w[i];
    if (i < 147456) { int o = i / 192, k = i % 192; Wfc1[i] = (bf16)fc1_w[k * 768 + o]; }
    if (i < 147456) { int o = i / 768, k = i % 768; Wfc2[i] = (bf16)fc2_w[k * 192 + o]; }
    if (i < 384) biasfv[i] = i < 192 ? f_b[i] : v_b[i - 192];
}

// ---------------- GroupNorm stats for GN1 (2-stage, deterministic) ----------------
__global__ __launch_bounds__(256) void gn_stats(const float* __restrict__ X, float2* __restrict__ part)
{
    const int b = blockIdx.y, seg = blockIdx.x;   // grid (16, 64)
    const float4* p = (const float4*)(X + (size_t)b * SAMP_ELEMS + (size_t)seg * 12288);
    float s = 0.f, q = 0.f;
    for (int i = threadIdx.x; i < 3072; i += 256) {
        float4 v = p[i];
        s += v.x + v.y + v.z + v.w;
        q += v.x * v.x + v.y * v.y + v.z * v.z + v.w * v.w;
    }
    __shared__ float bs[256], bq[256];
    const int t = threadIdx.x;
    bs[t] = s; bq[t] = q; __syncthreads();
    for (int off = 128; off > 0; off >>= 1) {
        if (t < off) { bs[t] += bs[t + off]; bq[t] += bq[t + off]; }
        __syncthreads();
    }
    if (t == 0) part[b * 16 + seg] = make_float2(bs[0], bq[0]);
}

__device__ inline float2 gn_mv_n(const float2* __restrict__ part, int b, int n)
{
    float s = 0.f, q = 0.f;
    for (int i = 0; i < n; ++i) { float2 v = part[b * n + i]; s += v.x; q += v.y; }
    const float mean = s * (1.f / (float)SAMP_ELEMS);
    const float var = q * (1.f / (float)SAMP_ELEMS) - mean * mean;
    float2 r; r.x = mean; r.y = rsqrtf(var + 1e-5f);
    return r;
}

// ---------------- GN1 normalize + NCHW->NHWC transpose -> bf16 ----------------
__global__ __launch_bounds__(256) void gn_norm_t(
    const float* __restrict__ X, const float2* __restrict__ part,
    const float* __restrict__ w, const float* __restrict__ bias, bf16* __restrict__ XN)
{
    const int b = blockIdx.z;
    const int p0 = blockIdx.x * 64, c0 = blockIdx.y * 64;
    const float2 mv = gn_mv_n(part, b, 16);
    __shared__ float lds[64][65];
    const int tx = threadIdx.x & 63, ty = threadIdx.x >> 6;
    for (int cc = ty; cc < 64; cc += 4) {
        const int c = c0 + cc;
        const float v = X[((size_t)b * DIMC + c) * 1024 + p0 + tx];
        lds[cc][tx] = (v - mv.x) * mv.y * w[c] + bias[c];
    }
    __syncthreads();
    for (int pp = ty; pp < 64; pp += 4) {
        XN[((size_t)b * 1024 + p0 + pp) * DIMC + c0 + tx] = (bf16)lds[tx][pp];
    }
}

// ---------------- MFMA GEMM: C[M][N] = A[M][K] @ W[N][K]^T + bias ----------------
// EPI 0: store bf16                          (f/v conv)
// EPI 2: X1 = x_nchw + ls1*acc -> f32 NHWC   (proj) + per-block GN2 partial stats
template<int EPI>
__global__ __launch_bounds__(256) void gemm_k(
    const bf16* __restrict__ A, const bf16* __restrict__ W,
    const float* __restrict__ bias, int N, int K,
    bf16* __restrict__ outb, float* __restrict__ outf,
    const float* __restrict__ resid, const float* __restrict__ ls,
    float2* __restrict__ pstats)
{
    __shared__ uint4 sA[64 * 24];
    __shared__ uint4 sW[64 * 24];
    const int t = threadIdx.x;
    const int m0 = blockIdx.y * 64;
    const int n0 = blockIdx.x * 64;
    const int lane = t & 63;
    const int wave = t >> 6;
    const int wm = wave >> 1, wn = wave & 1;
    const int lm = lane & 15, hi = lane >> 4;

    f32x4 acc00 = {0,0,0,0}, acc01 = {0,0,0,0}, acc10 = {0,0,0,0}, acc11 = {0,0,0,0};

    const int rA0 = wm * 32 + lm,      rA1 = wm * 32 + 16 + lm;
    const int rW0 = wn * 32 + lm,      rW1 = wn * 32 + 16 + lm;
    const bf16x8* fa = (const bf16x8*)sA;
    const bf16x8* fw = (const bf16x8*)sW;

    for (int kc = 0; kc < K; kc += 192) {
        for (int i = t; i < 64 * 24; i += 256) {
            const int r = i / 24, ci = i % 24;
            sA[r * 24 + (ci ^ (r & 7))] = *(const uint4*)(A + (size_t)(m0 + r) * K + kc + ci * 8);
            sW[r * 24 + (ci ^ (r & 7))] = *(const uint4*)(W + (size_t)(n0 + r) * K + kc + ci * 8);
        }
        __syncthreads();
#pragma unroll
        for (int ks = 0; ks < 6; ++ks) {
            const int cb = ks * 4 + hi;
            bf16x8 a0 = fa[rA0 * 24 + (cb ^ (rA0 & 7))];
            bf16x8 a1 = fa[rA1 * 24 + (cb ^ (rA1 & 7))];
            bf16x8 w0 = fw[rW0 * 24 + (cb ^ (rW0 & 7))];
            bf16x8 w1 = fw[rW1 * 24 + (cb ^ (rW1 & 7))];
            acc00 = __builtin_amdgcn_mfma_f32_16x16x32_bf16(a0, w0, acc00, 0, 0, 0);
            acc01 = __builtin_amdgcn_mfma_f32_16x16x32_bf16(a0, w1, acc01, 0, 0, 0);
            acc10 = __builtin_amdgcn_mfma_f32_16x16x32_bf16(a1, w0, acc10, 0, 0, 0);
            acc11 = __builtin_amdgcn_mfma_f32_16x16x32_bf16(a1, w1, acc11, 0, 0, 0);
        }
        __syncthreads();
    }

    float ps = 0.f, pq = 0.f;   // GN2 partial sums (EPI 2)
#pragma unroll
    for (int mt = 0; mt < 2; ++mt) {
#pragma unroll
        for (int nt = 0; nt < 2; ++nt) {
            f32x4 av = mt == 0 ? (nt == 0 ? acc00 : acc01) : (nt == 0 ? acc10 : acc11);
            const int nc = n0 + wn * 32 + nt * 16 + lm;
            const int mr = m0 + wm * 32 + mt * 16 + hi * 4;
            const float bv = bias[nc];
#pragma unroll
            for (int j = 0; j < 4; ++j) {
                const int m = mr + j;
                const float v = av[j] + bv;
                if constexpr (EPI == 0) {
                    outb[(size_t)m * N + nc] = (bf16)v;
                } else {
                    const int bb = m >> 10, p = m & 1023;
                    const float xv = resid[((size_t)bb * DIMC + nc) * 1024 + p];  // x NCHW
                    const float x1 = xv + ls[nc] * v;
                    outf[(size_t)m * DIMC + nc] = x1;                             // X1 NHWC f32
                    ps += x1; pq += x1 * x1;
                }
            }
        }
    }

    if constexpr (EPI == 2) {
        __shared__ float rs[256], rq[256];
        rs[t] = ps; rq[t] = pq; __syncthreads();
        for (int off = 128; off > 0; off >>= 1) {
            if (t < off) { rs[t] += rs[t + off]; rq[t] += rq[t + off]; }
            __syncthreads();
        }
        if (t == 0) {
            const int bb = blockIdx.y >> 4;
            const int slot = (blockIdx.y & 15) * 3 + blockIdx.x;   // 48 slots/sample
            pstats[bb * 48 + slot] = make_float2(rs[0], rq[0]);
        }
    }
}

// ---------------- fused MLP: out = X1 + ls2 * (GELU(GN2(X1)@W1+b1)@W2 + b2) ----------------
// One block = 64 tokens. hid never leaves the CU (12 chunks of 64 hid-cols).
__global__ __launch_bounds__(256) void mlp_k(
    const float* __restrict__ X1, const float2* __restrict__ part,
    const float* __restrict__ gw, const float* __restrict__ gb,
    const bf16* __restrict__ W1, const float* __restrict__ b1,
    const bf16* __restrict__ W2, const float* __restrict__ b2,
    const float* __restrict__ ls, float* __restrict__ out)
{
    __shared__ uint4 sA[64 * 24];    // 64 tokens x 192 ch (bf16, swizzled)
    __shared__ uint4 sW1[64 * 24];   // 64 hid x 192 ch
    __shared__ uint4 sW2[192 * 8];   // 192 out x 64 hid-k
    __shared__ bf16  sH[64 * 64];    // 64 tokens x 64 hid (swizzled 16B chunks)

    const int t = threadIdx.x;
    const int m0 = blockIdx.x * 64;
    const int bb = m0 >> 10;
    const float2 mv = gn_mv_n(part, bb, 48);

    // phase 0: stage sA = bf16(GN2(X1 tile))
    for (int cid = t; cid < 1536; cid += 256) {
        const int r = cid / 24, ci = cid % 24;
        const int c0 = ci * 8;
        const float* src = X1 + (size_t)(m0 + r) * 192 + c0;
        const float4 v0 = *(const float4*)(src);
        const float4 v1 = *(const float4*)(src + 4);
        const float4 w0 = *(const float4*)(gw + c0);
        const float4 w1 = *(const float4*)(gw + c0 + 4);
        const float4 g0 = *(const float4*)(gb + c0);
        const float4 g1 = *(const float4*)(gb + c0 + 4);
        bfu o;
        o.h[0] = (bf16)((v0.x - mv.x) * mv.y * w0.x + g0.x);
        o.h[1] = (bf16)((v0.y - mv.x) * mv.y * w0.y + g0.y);
        o.h[2] = (bf16)((v0.z - mv.x) * mv.y * w0.z + g0.z);
        o.h[3] = (bf16)((v0.w - mv.x) * mv.y * w0.w + g0.w);
        o.h[4] = (bf16)((v1.x - mv.x) * mv.y * w1.x + g1.x);
        o.h[5] = (bf16)((v1.y - mv.x) * mv.y * w1.y + g1.y);
        o.h[6] = (bf16)((v1.z - mv.x) * mv.y * w1.z + g1.z);
        o.h[7] = (bf16)((v1.w - mv.x) * mv.y * w1.w + g1.w);
        sA[r * 24 + (ci ^ (r & 7))] = o.u;
    }

    const int lane = t & 63, wave = t >> 6;
    const int wm = wave >> 1, wn = wave & 1;
    const int lm = lane & 15, hi = lane >> 4;
    const int rA0 = wm * 32 + lm, rA1 = rA0 + 16;
    const int rW0 = wn * 32 + lm, rW1 = rW0 + 16;
    const bf16x8* fa  = (const bf16x8*)sA;
    const bf16x8* fw1 = (const bf16x8*)sW1;
    const bf16x8* fw2 = (const bf16x8*)sW2;
    const bf16x8* fh  = (const bf16x8*)sH;

    f32x4 o0_0 = {0,0,0,0}, o0_1 = {0,0,0,0}, o0_2 = {0,0,0,0}, o0_3 = {0,0,0,0}, o0_4 = {0,0,0,0}, o0_5 = {0,0,0,0};
    f32x4 o1_0 = {0,0,0,0}, o1_1 = {0,0,0,0}, o1_2 = {0,0,0,0}, o1_3 = {0,0,0,0}, o1_4 = {0,0,0,0}, o1_5 = {0,0,0,0};

    for (int j = 0; j < 12; ++j) {
        // stage W1 chunk [64 hid rows][192] and W2 chunk [192 out rows][64]
        for (int cid = t; cid < 1536; cid += 256) {
            const int r = cid / 24, ci = cid % 24;
            sW1[r * 24 + (ci ^ (r & 7))] = *(const uint4*)(W1 + (size_t)(j * 64 + r) * 192 + ci * 8);
        }
        for (int cid = t; cid < 1536; cid += 256) {
            const int r = cid / 8, ci = cid % 8;
            sW2[r * 8 + (ci ^ (r & 7))] = *(const uint4*)(W2 + (size_t)r * 768 + j * 64 + ci * 8);
        }
        __syncthreads();   // staging visible (prev phase-2 finished at loop-end barrier)

        // phase 1: hid chunk = A @ W1_j
        f32x4 h00 = {0,0,0,0}, h01 = {0,0,0,0}, h10 = {0,0,0,0}, h11 = {0,0,0,0};
#pragma unroll
        for (int ks = 0; ks < 6; ++ks) {
            const int cb = ks * 4 + hi;
            bf16x8 a0 = fa[rA0 * 24 + (cb ^ (rA0 & 7))];
            bf16x8 a1 = fa[rA1 * 24 + (cb ^ (rA1 & 7))];
            bf16x8 w0 = fw1[rW0 * 24 + (cb ^ (rW0 & 7))];
            bf16x8 w1 = fw1[rW1 * 24 + (cb ^ (rW1 & 7))];
            h00 = __builtin_amdgcn_mfma_f32_16x16x32_bf16(a0, w0, h00, 0, 0, 0);
            h01 = __builtin_amdgcn_mfma_f32_16x16x32_bf16(a0, w1, h01, 0, 0, 0);
            h10 = __builtin_amdgcn_mfma_f32_16x16x32_bf16(a1, w0, h10, 0, 0, 0);
            h11 = __builtin_amdgcn_mfma_f32_16x16x32_bf16(a1, w1, h11, 0, 0, 0);
        }
        // bias + exact GELU -> bf16 -> sH
#pragma unroll
        for (int mt = 0; mt < 2; ++mt) {
#pragma unroll
            for (int nt = 0; nt < 2; ++nt) {
                const f32x4 hv = mt == 0 ? (nt == 0 ? h00 : h01) : (nt == 0 ? h10 : h11);
                const int hc = wn * 32 + nt * 16 + lm;
                const float bias1 = b1[j * 64 + hc];
                const int mrow = wm * 32 + mt * 16 + hi * 4;
#pragma unroll
                for (int jj = 0; jj < 4; ++jj) {
                    const float vv = hv[jj] + bias1;
                    const float g = 0.5f * vv * (1.f + erff(vv * 0.70710678118654752f));
                    const int m = mrow + jj;
                    sH[m * 64 + (((hc >> 3) ^ (m & 7)) << 3) + (hc & 7)] = (bf16)g;
                }
            }
        }
        __syncthreads();   // sH visible

        // phase 2: out_acc += H @ W2_j   (K = 64)
#pragma unroll
        for (int ks = 0; ks < 2; ++ks) {
            const int cb = ks * 4 + hi;
            bf16x8 a0 = fh[rA0 * 8 + (cb ^ (rA0 & 7))];
            bf16x8 a1 = fh[rA1 * 8 + (cb ^ (rA1 & 7))];
            const int rb = wn * 96 + lm;
            bf16x8 b0 = fw2[(rb +  0) * 8 + (cb ^ ((rb +  0) & 7))];
            bf16x8 b1v= fw2[(rb + 16) * 8 + (cb ^ ((rb + 16) & 7))];
            bf16x8 b2v= fw2[(rb + 32) * 8 + (cb ^ ((rb + 32) & 7))];
            bf16x8 b3 = fw2[(rb + 48) * 8 + (cb ^ ((rb + 48) & 7))];
            bf16x8 b4 = fw2[(rb + 64) * 8 + (cb ^ ((rb + 64) & 7))];
            bf16x8 b5 = fw2[(rb + 80) * 8 + (cb ^ ((rb + 80) & 7))];
            o0_0 = __builtin_amdgcn_mfma_f32_16x16x32_bf16(a0, b0,  o0_0, 0, 0, 0);
            o1_0 = __builtin_amdgcn_mfma_f32_16x16x32_bf16(a1, b0,  o1_0, 0, 0, 0);
            o0_1 = __builtin_amdgcn_mfma_f32_16x16x32_bf16(a0, b1v, o0_1, 0, 0, 0);
            o1_1 = __builtin_amdgcn_mfma_f32_16x16x32_bf16(a1, b1v, o1_1, 0, 0, 0);
            o0_2 = __builtin_amdgcn_mfma_f32_16x16x32_bf16(a0, b2v, o0_2, 0, 0, 0);
            o1_2 = __builtin_amdgcn_mfma_f32_16x16x32_bf16(a1, b2v, o1_2, 0, 0, 0);
            o0_3 = __builtin_amdgcn_mfma_f32_16x16x32_bf16(a0, b3,  o0_3, 0, 0, 0);
            o1_3 = __builtin_amdgcn_mfma_f32_16x16x32_bf16(a1, b3,  o1_3, 0, 0, 0);
            o0_4 = __builtin_amdgcn_mfma_f32_16x16x32_bf16(a0, b4,  o0_4, 0, 0, 0);
            o1_4 = __builtin_amdgcn_mfma_f32_16x16x32_bf16(a1, b4,  o1_4, 0, 0, 0);
            o0_5 = __builtin_amdgcn_mfma_f32_16x16x32_bf16(a0, b5,  o0_5, 0, 0, 0);
            o1_5 = __builtin_amdgcn_mfma_f32_16x16x32_bf16(a1, b5,  o1_5, 0, 0, 0);
        }
        __syncthreads();   // protect sW1/sW2/sH before next stage
    }

    // epilogue: out(NCHW) = X1 + ls2 * (acc + b2)
#pragma unroll
    for (int mt = 0; mt < 2; ++mt) {
#pragma unroll
        for (int nf = 0; nf < 6; ++nf) {
            f32x4 av;
            if (mt == 0) av = nf == 0 ? o0_0 : nf == 1 ? o0_1 : nf == 2 ? o0_2 : nf == 3 ? o0_3 : nf == 4 ? o0_4 : o0_5;
            else         av = nf == 0 ? o1_0 : nf == 1 ? o1_1 : nf == 2 ? o1_2 : nf == 3 ? o1_3 : nf == 4 ? o1_4 : o1_5;
            const int nc = wn * 96 + nf * 16 + lm;
            const int mr = wm * 32 + mt * 16 + hi * 4;
            const float b2v = b2[nc], lsv = ls[nc];
            const float* xp = X1 + (size_t)(m0 + mr) * 192 + nc;
            float4 ov;
            ov.x = xp[0]   + lsv * (av[0] + b2v);
            ov.y = xp[192] + lsv * (av[1] + b2v);
            ov.z = xp[384] + lsv * (av[2] + b2v);
            ov.w = xp[576] + lsv * (av[3] + b2v);
            *(float4*)(out + ((size_t)bb * DIMC + nc) * 1024 + (m0 & 1023) + mr) = ov;
        }
    }
}

// ---------------- cluster: one block per (b, head, fold1, fold2) group ----------------
__global__ __launch_bounds__(256) void cluster_k(
    const bf16* __restrict__ FV, bf16* __restrict__ Y,
    const float* __restrict__ alpha_p, const float* __restrict__ beta_p)
{
    __shared__ __align__(16) char u_raw[25600];
    __shared__ float cf[4][24], cv[4][24];
    __shared__ float partial[8][4][24];
    __shared__ int   cntp[4][4];
    __shared__ float aggL[4][24];
    __shared__ int   bestL[256];

    const int g = blockIdx.x;
    const int bb = g >> 5, e = (g >> 2) & 7, f1 = (g >> 1) & 1, f2 = g & 1;
    const int t = threadIdx.x;
    const int wi = t >> 4, hj = t & 15;
    const int p = (f1 * 16 + wi) * 32 + (f2 * 16 + hj);
    const size_t tok = (size_t)bb * 1024 + p;

    const bf16x8* src = (const bf16x8*)(FV + tok * 384);
    bf16x8 hf0 = src[e * 3 + 0], hf1 = src[e * 3 + 1], hf2 = src[e * 3 + 2];
    bf16x8 hv0 = src[24 + e * 3 + 0], hv1 = src[24 + e * 3 + 1], hv2 = src[24 + e * 3 + 2];

    bf16* lfv = (bf16*)u_raw;                    // [256][48]
    {
        bf16x8* row = (bf16x8*)(lfv + t * 48);
        row[0] = hf0; row[1] = hf1; row[2] = hf2;
        row[3] = hv0; row[4] = hv1; row[5] = hv2;
    }
    float freg[24];
#pragma unroll
    for (int j = 0; j < 8; ++j) {
        freg[j] = (float)hf0[j]; freg[8 + j] = (float)hf1[j]; freg[16 + j] = (float)hf2[j];
    }
    __syncthreads();

    if (t < 192) {
        const int team = t / 96;
        const int idx = t % 96;
        const int m = idx / 24, c = idx % 24;
        const int pw = m >> 1, ph = m & 1;
        float s = 0.f;
        for (int a = 0; a < 8; ++a) {
            const int nb = (pw * 8 + a) * 16 + ph * 8;
#pragma unroll
            for (int bj = 0; bj < 8; ++bj)
                s += (float)lfv[(nb + bj) * 48 + team * 24 + c];
        }
        if (team) cv[m][c] = s * (1.f / 64.f);
        else      cf[m][c] = s * (1.f / 64.f);
    }
    __syncthreads();

    float nrm = 0.f;
#pragma unroll
    for (int c = 0; c < 24; ++c) nrm += freg[c] * freg[c];
    const float invf = 1.f / fmaxf(sqrtf(nrm), 1e-12f);
    const float alpha = alpha_p[0], beta = beta_p[0];
    float bestv = -1.f; int best = 0;
#pragma unroll
    for (int m = 0; m < 4; ++m) {
        float d = 0.f, cs = 0.f;
#pragma unroll
        for (int c = 0; c < 24; ++c) {
            const float cfv = cf[m][c];
            d += cfv * freg[c];
            cs += cfv * cfv;
        }
        const float z = beta + alpha * d * (1.f / fmaxf(sqrtf(cs), 1e-12f)) * invf;
        const float sim = 1.f / (1.f + expf(-z));
        if (sim > bestv) { bestv = sim; best = m; }
    }

    {
        const unsigned long long q0 = __ballot(best == 0);
        const unsigned long long q1 = __ballot(best == 1);
        const unsigned long long q2 = __ballot(best == 2);
        const unsigned long long q3 = __ballot(best == 3);
        if ((t & 63) == 0) {
            const int w = t >> 6;
            cntp[w][0] = __popcll(q0); cntp[w][1] = __popcll(q1);
            cntp[w][2] = __popcll(q2); cntp[w][3] = __popcll(q3);
        }
    }

    float (*pvL)[25] = (float (*)[25])u_raw;
#pragma unroll
    for (int j = 0; j < 8; ++j) {
        pvL[t][j]      = bestv * (float)hv0[j];
        pvL[t][8 + j]  = bestv * (float)hv1[j];
        pvL[t][16 + j] = bestv * (float)hv2[j];
    }
    bestL[t] = best;
    __syncthreads();

    if (t < 192) {
        const int seg = t / 24, c = t % 24;
        float a0 = 0.f, a1 = 0.f, a2 = 0.f, a3 = 0.f;
        const int nb = seg * 32;
        for (int i = 0; i < 32; ++i) {
            const int n = nb + i;
            const int bm = bestL[n];
            const float x = pvL[n][c];
            a0 += (bm == 0) ? x : 0.f;
            a1 += (bm == 1) ? x : 0.f;
            a2 += (bm == 2) ? x : 0.f;
            a3 += (bm == 3) ? x : 0.f;
        }
        partial[seg][0][c] = a0; partial[seg][1][c] = a1;
        partial[seg][2][c] = a2; partial[seg][3][c] = a3;
    }
    __syncthreads();

    if (t < 96) {
        const int m = t / 24, c = t % 24;
        float s = 0.f;
#pragma unroll
        for (int seg = 0; seg < 8; ++seg) s += partial[seg][m][c];
        const int cnt = cntp[0][m] + cntp[1][m] + cntp[2][m] + cntp[3][m];
        aggL[m][c] = (s + cv[m][c]) / ((float)cnt + 1.f);
    }
    __syncthreads();

    const float sv = bestv; const int bm = best;
    bf16x8 z0, z1, z2;
#pragma unroll
    for (int j = 0; j < 8; ++j) {
        z0[j] = (bf16)(aggL[bm][j] * sv);
        z1[j] = (bf16)(aggL[bm][8 + j] * sv);
        z2[j] = (bf16)(aggL[bm][16 + j] * sv);
    }
    bf16x8* dst = (bf16x8*)(Y + tok * DIMC + e * 24);
    dst[0] = z0; dst[1] = z1; dst[2] = z2;
}

// ---------------- launch ----------------
extern "C" void kernel_launch(void* const* d_in, const int* in_sizes, int n_in,
                              void* d_out, int out_size, void* d_ws, size_t ws_size,
                              hipStream_t stream)
{
    (void)in_sizes; (void)n_in; (void)out_size; (void)ws_size;
    const float* x      = (const float*)d_in[0];
    const float* gn1_w  = (const float*)d_in[1];
    const float* gn1_b  = (const float*)d_in[2];
    const float* f_w    = (const float*)d_in[3];
    const float* f_b    = (const float*)d_in[4];
    const float* v_w    = (const float*)d_in[5];
    const float* v_b    = (const float*)d_in[6];
    const float* proj_w = (const float*)d_in[7];
    const float* proj_b = (const float*)d_in[8];
    const float* alpha  = (const float*)d_in[9];
    const float* beta   = (const float*)d_in[10];
    const float* ls1    = (const float*)d_in[11];
    const float* gn2_w  = (const float*)d_in[12];
    const float* gn2_b  = (const float*)d_in[13];
    const float* fc1_w  = (const float*)d_in[14];
    const float* fc1_b  = (const float*)d_in[15];
    const float* fc2_w  = (const float*)d_in[16];
    const float* fc2_b  = (const float*)d_in[17];
    const float* ls2    = (const float*)d_in[18];

    char* ws = (char*)d_ws;
    float2* part1 = (float2*)(ws + OFF_PART1);
    float2* part2 = (float2*)(ws + OFF_PART2);
    float* biasfv = (float*)(ws + OFF_BIASFV);
    bf16* Wfv   = (bf16*)(ws + OFF_WFV);
    bf16* Wproj = (bf16*)(ws + OFF_WPROJ);
    bf16* Wfc1  = (bf16*)(ws + OFF_WFC1);
    bf16* Wfc2  = (bf16*)(ws + OFF_WFC2);
    bf16* XN    = (bf16*)(ws + OFF_XN);
    bf16* FVb   = (bf16*)(ws + OFF_FV);
    bf16* Yb    = (bf16*)(ws + OFF_Y);
    float* X1   = (float*)(ws + OFF_X1);
    float* out  = (float*)d_out;

    prep_w<<<576, 256, 0, stream>>>(f_w, v_w, proj_w, fc1_w, fc2_w, f_b, v_b,
                                    Wfv, Wproj, Wfc1, Wfc2, biasfv);
    gn_stats<<<dim3(16, 64), 256, 0, stream>>>(x, part1);
    gn_norm_t<<<dim3(16, 3, 64), 256, 0, stream>>>(x, part1, gn1_w, gn1_b, XN);
    gemm_k<0><<<dim3(6, 1024), 256, 0, stream>>>(XN, Wfv, biasfv, 384, 192,
                                                 FVb, nullptr, nullptr, nullptr, nullptr);
    cluster_k<<<2048, 256, 0, stream>>>(FVb, Yb, alpha, beta);
    gemm_k<2><<<dim3(3, 1024), 256, 0, stream>>>(Yb, Wproj, proj_b, 192, 192,
                                                 nullptr, X1, x, ls1, part2);
    mlp_k<<<1024, 256, 0, stream>>>(X1, part2, gn2_w, gn2_b,
                                    Wfc1, fc1_b, Wfc2, fc2_b, ls2, out);
}